// Round 1
// baseline (2506.512 us; speedup 1.0000x reference)
//
#include <hip/hip_runtime.h>

#define D_IN 128
#define D_HID 64
#define N_GRAPHS 1024
#define N_CLASSES 10

// ---------------- degree / dinv ----------------

__global__ void init_deg(float* __restrict__ deg, int n) {
    int i = blockIdx.x * blockDim.x + threadIdx.x;
    if (i < n) deg[i] = 1.0f;  // self-loop
}

__global__ void count_deg(const int* __restrict__ dst, float* __restrict__ deg, int nE) {
    int i = blockIdx.x * blockDim.x + threadIdx.x;
    if (i < nE) atomicAdd(&deg[dst[i]], 1.0f);
}

__global__ void finish_dinv(float* __restrict__ deg, int n) {
    int i = blockIdx.x * blockDim.x + threadIdx.x;
    if (i < n) deg[i] = 1.0f / sqrtf(deg[i]);  // deg >= 1 always
}

// ---------------- dense GEMM: H[n,64] = act(X + bias) @ W[K,64] ----------------
// act applied to the INPUT X (fuses previous layer's bias+relu). bias==nullptr -> raw X.

template <int K>
__global__ __launch_bounds__(256) void gemm_nodes(
    const float* __restrict__ X, const float* __restrict__ W,
    const float* __restrict__ bias, int relu,
    float* __restrict__ H, int n) {
    __shared__ float wlds[K * 64];
    __shared__ float xs[4][K];
    int tid = threadIdx.x;
    for (int i = tid; i < K * 64; i += 256) wlds[i] = W[i];
    int wave = tid >> 6, lane = tid & 63;
    for (int row0 = blockIdx.x * 4; row0 < n; row0 += gridDim.x * 4) {
        int row = row0 + wave;
        __syncthreads();  // W visible (iter 0); xs no longer being read (iter >0)
        if (row < n) {
            for (int k = lane; k < K; k += 64) {
                float v = X[(size_t)row * K + k];
                if (bias != nullptr) {
                    v += bias[k];
                    if (relu) v = fmaxf(v, 0.0f);
                }
                xs[wave][k] = v;
            }
        }
        __syncthreads();
        if (row < n) {
            float acc = 0.0f;
#pragma unroll
            for (int k = 0; k < K; ++k)
                acc = fmaf(xs[wave][k], wlds[k * 64 + lane], acc);
            H[(size_t)row * 64 + lane] = acc;
        }
    }
}

// ---------------- B = dinv^2 * A  (self-loop term; also zero-initializes B) ----------------

__global__ void self_init(const float* __restrict__ A, const float* __restrict__ dinv,
                          float* __restrict__ B, long total) {
    long i = (long)blockIdx.x * blockDim.x + threadIdx.x;
    if (i < total) {
        int node = (int)(i >> 6);
        float di = dinv[node];
        B[i] = di * di * A[i];
    }
}

// ---------------- edge scatter: B[dst] += dinv[src]*dinv[dst] * A[src] ----------------
// one wave per edge per iteration; lane = feature index (64 feats, 256B coalesced)

__global__ __launch_bounds__(256) void scatter_edges(
    const int* __restrict__ src, const int* __restrict__ dst,
    const float* __restrict__ dinv, const float* __restrict__ A,
    float* __restrict__ B, int nE) {
    int gtid = blockIdx.x * blockDim.x + threadIdx.x;
    int wid = gtid >> 6, lane = gtid & 63;
    int nw = (gridDim.x * blockDim.x) >> 6;
    for (int e = wid; e < nE; e += nw) {
        int s = src[e], d = dst[e];
        float w = dinv[s] * dinv[d];
        float v = A[((size_t)s << 6) + lane];
        atomicAdd(&B[((size_t)d << 6) + lane], w * v);
    }
}

// ---------------- mean-pool accumulate: sums[batch[n]] += B[n] + b3; cnt[g] += 1 ----------------

__global__ __launch_bounds__(256) void pool_nodes(
    const float* __restrict__ B, const float* __restrict__ b3,
    const int* __restrict__ batch, float* __restrict__ sums,
    float* __restrict__ cnt, int n) {
    int gtid = blockIdx.x * blockDim.x + threadIdx.x;
    int wid = gtid >> 6, lane = gtid & 63;
    int nw = (gridDim.x * blockDim.x) >> 6;
    for (int node = wid; node < n; node += nw) {
        int g = batch[node];
        float v = B[((size_t)node << 6) + lane] + b3[lane];
        atomicAdd(&sums[((size_t)g << 6) + lane], v);
        if (lane == 0) atomicAdd(&cnt[g], 1.0f);
    }
}

// ---------------- final: out[g,c] = (sums[g]/cnt[g]) . Wl[:,c] + bl[c] ----------------

__global__ void final_linear(const float* __restrict__ sums, const float* __restrict__ cnt,
                             const float* __restrict__ Wl, const float* __restrict__ bl,
                             float* __restrict__ out) {
    int idx = blockIdx.x * blockDim.x + threadIdx.x;
    if (idx >= N_GRAPHS * N_CLASSES) return;
    int g = idx / N_CLASSES, c = idx - g * N_CLASSES;
    float inv = 1.0f / fmaxf(cnt[g], 1.0f);
    float acc = bl[c];
#pragma unroll
    for (int d = 0; d < D_HID; ++d)
        acc = fmaf(sums[(g << 6) + d] * inv, Wl[d * N_CLASSES + c], acc);
    out[idx] = acc;
}

extern "C" void kernel_launch(void* const* d_in, const int* in_sizes, int n_in,
                              void* d_out, int out_size, void* d_ws, size_t ws_size,
                              hipStream_t stream) {
    const float* x     = (const float*)d_in[0];
    const int*   ei    = (const int*)d_in[1];
    const int*   batch = (const int*)d_in[2];
    const float* W1 = (const float*)d_in[3];
    const float* b1 = (const float*)d_in[4];
    const float* W2 = (const float*)d_in[5];
    const float* b2 = (const float*)d_in[6];
    const float* W3 = (const float*)d_in[7];
    const float* b3 = (const float*)d_in[8];
    const float* Wl = (const float*)d_in[9];
    const float* bl = (const float*)d_in[10];

    int n = in_sizes[0] / D_IN;
    int E = in_sizes[1] / 2;
    const int* src = ei;
    const int* dst = ei + E;

    // workspace layout (floats)
    size_t nAl = ((size_t)n + 255) & ~(size_t)255;
    float* dinv = (float*)d_ws;
    float* A    = dinv + nAl;            // n*64
    float* B    = A + (size_t)n * 64;    // n*64
    float* sums = B + (size_t)n * 64;    // 1024*64
    float* cnt  = sums + N_GRAPHS * 64;  // 1024

    int blk = 256;
    int gN  = (n + blk - 1) / blk;
    int gE  = (E + blk - 1) / blk;
    int gEl = (int)(((size_t)n * 64 + blk - 1) / blk);
    int gGemm = (n + 3) / 4;

    // degrees
    init_deg<<<gN, blk, 0, stream>>>(dinv, n);
    count_deg<<<gE, blk, 0, stream>>>(dst, dinv, E);
    finish_dinv<<<gN, blk, 0, stream>>>(dinv, n);

    // layer 1
    gemm_nodes<D_IN><<<gGemm, blk, 0, stream>>>(x, W1, nullptr, 0, A, n);
    self_init<<<gEl, blk, 0, stream>>>(A, dinv, B, (long)n * 64);
    scatter_edges<<<4096, blk, 0, stream>>>(src, dst, dinv, A, B, E);

    // layer 2 (input act: relu(B + b1))
    gemm_nodes<D_HID><<<gGemm, blk, 0, stream>>>(B, W2, b1, 1, A, n);
    self_init<<<gEl, blk, 0, stream>>>(A, dinv, B, (long)n * 64);
    scatter_edges<<<4096, blk, 0, stream>>>(src, dst, dinv, A, B, E);

    // layer 3 (input act: relu(B + b2))
    gemm_nodes<D_HID><<<gGemm, blk, 0, stream>>>(B, W3, b2, 1, A, n);
    self_init<<<gEl, blk, 0, stream>>>(A, dinv, B, (long)n * 64);
    scatter_edges<<<4096, blk, 0, stream>>>(src, dst, dinv, A, B, E);

    // pool (+b3) and final linear
    hipMemsetAsync(sums, 0, (N_GRAPHS * 64 + N_GRAPHS) * sizeof(float), stream);
    pool_nodes<<<2048, blk, 0, stream>>>(B, b3, batch, sums, cnt, n);
    final_linear<<<(N_GRAPHS * N_CLASSES + blk - 1) / blk, blk, 0, stream>>>(
        sums, cnt, Wl, bl, (float*)d_out);
}

// Round 2
// 1062.521 us; speedup vs baseline: 2.3590x; 2.3590x over previous
//
#include <hip/hip_runtime.h>

#define D_IN 128
#define D_HID 64
#define N_GRAPHS 1024
#define N_CLASSES 10

// ================= degree count + dinv =================

__global__ void count_deg_int(const int* __restrict__ dst, int* __restrict__ counts, int nE) {
    int i = blockIdx.x * blockDim.x + threadIdx.x;
    if (i < nE) atomicAdd(&counts[dst[i]], 1);
}

__global__ void compute_dinv(const int* __restrict__ counts, float* __restrict__ dinv, int n) {
    int i = blockIdx.x * blockDim.x + threadIdx.x;
    if (i < n) dinv[i] = 1.0f / sqrtf((float)(counts[i] + 1));  // +1 self-loop
}

// ================= 3-kernel exclusive-ish scan (inclusive over counts) =================
// scan1: per-block inclusive scan of data[0..n), block size 1024, writes blocksums
__global__ __launch_bounds__(1024) void scan1(int* __restrict__ data, int n, int* __restrict__ bsum) {
    __shared__ int tile[1024];
    int tid = threadIdx.x;
    int i = blockIdx.x * 1024 + tid;
    int v = (i < n) ? data[i] : 0;
    tile[tid] = v;
    __syncthreads();
    for (int off = 1; off < 1024; off <<= 1) {
        int t = (tid >= off) ? tile[tid - off] : 0;
        __syncthreads();
        tile[tid] += t;
        __syncthreads();
    }
    if (i < n) data[i] = tile[tid];
    if (tid == 1023) bsum[blockIdx.x] = tile[1023];
}

// scan2: single block inclusive scan of nb blocksums (nb <= 1024)
__global__ __launch_bounds__(1024) void scan2(int* __restrict__ bsum, int nb) {
    __shared__ int tile[1024];
    int tid = threadIdx.x;
    tile[tid] = (tid < nb) ? bsum[tid] : 0;
    __syncthreads();
    for (int off = 1; off < 1024; off <<= 1) {
        int t = (tid >= off) ? tile[tid - off] : 0;
        __syncthreads();
        tile[tid] += t;
        __syncthreads();
    }
    if (tid < nb) bsum[tid] = tile[tid];
}

// scan3: add scanned blocksum[b-1] to block b's elements
__global__ __launch_bounds__(1024) void scan3(int* __restrict__ data, int n, const int* __restrict__ bsum) {
    int b = blockIdx.x + 1;
    int i = b * 1024 + threadIdx.x;
    if (i < n) data[i] += bsum[b - 1];
}

__global__ void copy_cursor(const int* __restrict__ rowptr, int* __restrict__ cursor, int n) {
    int i = blockIdx.x * blockDim.x + threadIdx.x;
    if (i < n) cursor[i] = rowptr[i];
}

__global__ void fill_csr(const int* __restrict__ src, const int* __restrict__ dst,
                         int* __restrict__ cursor, int* __restrict__ csr_src, int nE) {
    int i = blockIdx.x * blockDim.x + threadIdx.x;
    if (i < nE) {
        int pos = atomicAdd(&cursor[dst[i]], 1);
        csr_src[pos] = src[i];
    }
}

// ================= dense GEMM: H[n,64] = act(X + bias) @ W[K,64] =================

template <int K>
__global__ __launch_bounds__(256) void gemm_nodes(
    const float* __restrict__ X, const float* __restrict__ W,
    const float* __restrict__ bias, int relu,
    float* __restrict__ H, int n) {
    __shared__ float wlds[K * 64];
    __shared__ float xs[4][K];
    int tid = threadIdx.x;
    for (int i = tid; i < K * 64; i += 256) wlds[i] = W[i];
    int wave = tid >> 6, lane = tid & 63;
    for (int row0 = blockIdx.x * 4; row0 < n; row0 += gridDim.x * 4) {
        int row = row0 + wave;
        __syncthreads();
        if (row < n) {
            for (int k = lane; k < K; k += 64) {
                float v = X[(size_t)row * K + k];
                if (bias != nullptr) {
                    v += bias[k];
                    if (relu) v = fmaxf(v, 0.0f);
                }
                xs[wave][k] = v;
            }
        }
        __syncthreads();
        if (row < n) {
            float acc = 0.0f;
#pragma unroll
            for (int k = 0; k < K; ++k)
                acc = fmaf(xs[wave][k], wlds[k * 64 + lane], acc);
            H[(size_t)row * 64 + lane] = acc;
        }
    }
}

// ================= CSR gather aggregation =================
// B[d] = dinv[d]^2 * A[d] + sum_{e in CSR[d]} dinv[d]*dinv[src_e] * A[src_e]
// one wave per node, lane = feature; 4 edges in flight per wave

__global__ __launch_bounds__(256) void gather_agg(
    const int* __restrict__ rowptr, const int* __restrict__ csr_src,
    const float* __restrict__ dinv, const float* __restrict__ A,
    float* __restrict__ B, int n) {
    int gtid = blockIdx.x * blockDim.x + threadIdx.x;
    int wid = gtid >> 6, lane = gtid & 63;
    int nw = (gridDim.x * blockDim.x) >> 6;
    for (int d = wid; d < n; d += nw) {
        float dd = dinv[d];
        int e0 = rowptr[d], e1 = rowptr[d + 1];
        float acc = dd * dd * A[((size_t)d << 6) + lane];
        int e = e0;
        for (; e + 4 <= e1; e += 4) {
            int s0 = csr_src[e], s1 = csr_src[e + 1], s2 = csr_src[e + 2], s3 = csr_src[e + 3];
            float w0 = dinv[s0], w1 = dinv[s1], w2 = dinv[s2], w3 = dinv[s3];
            float v0 = A[((size_t)s0 << 6) + lane];
            float v1 = A[((size_t)s1 << 6) + lane];
            float v2 = A[((size_t)s2 << 6) + lane];
            float v3 = A[((size_t)s3 << 6) + lane];
            acc = fmaf(dd * w0, v0, acc);
            acc = fmaf(dd * w1, v1, acc);
            acc = fmaf(dd * w2, v2, acc);
            acc = fmaf(dd * w3, v3, acc);
        }
        for (; e < e1; ++e) {
            int s = csr_src[e];
            acc = fmaf(dd * dinv[s], A[((size_t)s << 6) + lane], acc);
        }
        B[((size_t)d << 6) + lane] = acc;
    }
}

// ================= mean pool + final linear =================

__global__ __launch_bounds__(256) void pool_nodes(
    const float* __restrict__ B, const float* __restrict__ b3,
    const int* __restrict__ batch, float* __restrict__ sums,
    float* __restrict__ cnt, int n) {
    int gtid = blockIdx.x * blockDim.x + threadIdx.x;
    int wid = gtid >> 6, lane = gtid & 63;
    int nw = (gridDim.x * blockDim.x) >> 6;
    for (int node = wid; node < n; node += nw) {
        int g = batch[node];
        float v = B[((size_t)node << 6) + lane] + b3[lane];
        atomicAdd(&sums[((size_t)g << 6) + lane], v);
        if (lane == 0) atomicAdd(&cnt[g], 1.0f);
    }
}

__global__ void final_linear(const float* __restrict__ sums, const float* __restrict__ cnt,
                             const float* __restrict__ Wl, const float* __restrict__ bl,
                             float* __restrict__ out) {
    int idx = blockIdx.x * blockDim.x + threadIdx.x;
    if (idx >= N_GRAPHS * N_CLASSES) return;
    int g = idx / N_CLASSES, c = idx - g * N_CLASSES;
    float inv = 1.0f / fmaxf(cnt[g], 1.0f);
    float acc = bl[c];
#pragma unroll
    for (int d = 0; d < D_HID; ++d)
        acc = fmaf(sums[(g << 6) + d] * inv, Wl[d * N_CLASSES + c], acc);
    out[idx] = acc;
}

extern "C" void kernel_launch(void* const* d_in, const int* in_sizes, int n_in,
                              void* d_out, int out_size, void* d_ws, size_t ws_size,
                              hipStream_t stream) {
    const float* x     = (const float*)d_in[0];
    const int*   ei    = (const int*)d_in[1];
    const int*   batch = (const int*)d_in[2];
    const float* W1 = (const float*)d_in[3];
    const float* b1 = (const float*)d_in[4];
    const float* W2 = (const float*)d_in[5];
    const float* b2 = (const float*)d_in[6];
    const float* W3 = (const float*)d_in[7];
    const float* b3 = (const float*)d_in[8];
    const float* Wl = (const float*)d_in[9];
    const float* bl = (const float*)d_in[10];

    int n = in_sizes[0] / D_IN;
    int E = in_sizes[1] / 2;
    const int* src = ei;
    const int* dst = ei + E;

    // workspace layout
    size_t off = 0;
    auto alloc = [&](size_t elems) {
        void* p = (char*)d_ws + off;
        off += ((elems * 4 + 255) & ~(size_t)255);
        return p;
    };
    int*   rowptr  = (int*)alloc(n + 1);
    int*   cursor  = (int*)alloc(n);
    int*   bsum    = (int*)alloc(1024);
    int*   csr_src = (int*)alloc(E);
    float* dinv    = (float*)alloc(n);
    float* A       = (float*)alloc((size_t)n * 64);
    float* B       = (float*)alloc((size_t)n * 64);
    float* sums    = (float*)alloc(N_GRAPHS * 64);
    float* cnt     = (float*)alloc(N_GRAPHS);

    int blk = 256;
    int gN  = (n + blk - 1) / blk;
    int gE  = (E + blk - 1) / blk;
    int gGemm = (n + 3) / 4;
    int nb  = (n + 1023) / 1024;  // scan blocks over n counts

    // ---- CSR build (once, reused by all 3 layers) ----
    hipMemsetAsync(rowptr, 0, (size_t)(n + 1) * sizeof(int), stream);
    count_deg_int<<<gE, blk, 0, stream>>>(dst, rowptr + 1, E);
    compute_dinv<<<gN, blk, 0, stream>>>(rowptr + 1, dinv, n);
    scan1<<<nb, 1024, 0, stream>>>(rowptr + 1, n, bsum);
    scan2<<<1, 1024, 0, stream>>>(bsum, nb);
    if (nb > 1) scan3<<<nb - 1, 1024, 0, stream>>>(rowptr + 1, n, bsum);
    copy_cursor<<<gN, blk, 0, stream>>>(rowptr, cursor, n);
    fill_csr<<<gE, blk, 0, stream>>>(src, dst, cursor, csr_src, E);

    // ---- layer 1 ----
    gemm_nodes<D_IN><<<gGemm, blk, 0, stream>>>(x, W1, nullptr, 0, A, n);
    gather_agg<<<2048, blk, 0, stream>>>(rowptr, csr_src, dinv, A, B, n);

    // ---- layer 2 ----
    gemm_nodes<D_HID><<<gGemm, blk, 0, stream>>>(B, W2, b1, 1, A, n);
    gather_agg<<<2048, blk, 0, stream>>>(rowptr, csr_src, dinv, A, B, n);

    // ---- layer 3 ----
    gemm_nodes<D_HID><<<gGemm, blk, 0, stream>>>(B, W3, b2, 1, A, n);
    gather_agg<<<2048, blk, 0, stream>>>(rowptr, csr_src, dinv, A, B, n);

    // ---- pool + final ----
    hipMemsetAsync(sums, 0, (N_GRAPHS * 64 + N_GRAPHS) * sizeof(float), stream);
    pool_nodes<<<2048, blk, 0, stream>>>(B, b3, batch, sums, cnt, n);
    final_linear<<<(N_GRAPHS * N_CLASSES + blk - 1) / blk, blk, 0, stream>>>(
        sums, cnt, Wl, bl, (float*)d_out);
}

// Round 3
// 915.455 us; speedup vs baseline: 2.7380x; 1.1606x over previous
//
#include <hip/hip_runtime.h>
#include <hip/hip_fp16.h>

#define D_IN 128
#define D_HID 64
#define N_GRAPHS 1024
#define N_CLASSES 10

// ================= degree count + dinv =================

__global__ void count_deg_int(const int* __restrict__ dst, int* __restrict__ counts, int nE) {
    int i = blockIdx.x * blockDim.x + threadIdx.x;
    if (i < nE) atomicAdd(&counts[dst[i]], 1);
}

__global__ void compute_dinv(const int* __restrict__ counts, float* __restrict__ dinv, int n) {
    int i = blockIdx.x * blockDim.x + threadIdx.x;
    if (i < n) dinv[i] = 1.0f / sqrtf((float)(counts[i] + 1));  // +1 self-loop
}

// ================= scan (inclusive over counts) =================

__global__ __launch_bounds__(1024) void scan1(int* __restrict__ data, int n, int* __restrict__ bsum) {
    __shared__ int tile[1024];
    int tid = threadIdx.x;
    int i = blockIdx.x * 1024 + tid;
    int v = (i < n) ? data[i] : 0;
    tile[tid] = v;
    __syncthreads();
    for (int off = 1; off < 1024; off <<= 1) {
        int t = (tid >= off) ? tile[tid - off] : 0;
        __syncthreads();
        tile[tid] += t;
        __syncthreads();
    }
    if (i < n) data[i] = tile[tid];
    if (tid == 1023) bsum[blockIdx.x] = tile[1023];
}

__global__ __launch_bounds__(1024) void scan2(int* __restrict__ bsum, int nb) {
    __shared__ int tile[1024];
    int tid = threadIdx.x;
    tile[tid] = (tid < nb) ? bsum[tid] : 0;
    __syncthreads();
    for (int off = 1; off < 1024; off <<= 1) {
        int t = (tid >= off) ? tile[tid - off] : 0;
        __syncthreads();
        tile[tid] += t;
        __syncthreads();
    }
    if (tid < nb) bsum[tid] = tile[tid];
}

__global__ __launch_bounds__(1024) void scan3(int* __restrict__ data, int n, const int* __restrict__ bsum) {
    int b = blockIdx.x + 1;
    int i = b * 1024 + threadIdx.x;
    if (i < n) data[i] += bsum[b - 1];
}

__global__ void copy_cursor(const int* __restrict__ rowptr, int* __restrict__ cursor, int n) {
    int i = blockIdx.x * blockDim.x + threadIdx.x;
    if (i < n) cursor[i] = rowptr[i];
}

__global__ void fill_csr(const int* __restrict__ src, const int* __restrict__ dst,
                         int* __restrict__ cursor, int* __restrict__ csr_src, int nE) {
    int i = blockIdx.x * blockDim.x + threadIdx.x;
    if (i < nE) {
        int pos = atomicAdd(&cursor[dst[i]], 1);
        csr_src[pos] = src[i];
    }
}

// ================= dense GEMM: H[n,64] = act(X + bias) @ W[K,64], fp16 output =================

template <int K>
__global__ __launch_bounds__(256) void gemm_nodes(
    const float* __restrict__ X, const float* __restrict__ W,
    const float* __restrict__ bias, int relu,
    __half* __restrict__ H, int n) {
    __shared__ float wlds[K * 64];
    __shared__ float xs[4][K];
    int tid = threadIdx.x;
    for (int i = tid; i < K * 64; i += 256) wlds[i] = W[i];
    int wave = tid >> 6, lane = tid & 63;
    for (int row0 = blockIdx.x * 4; row0 < n; row0 += gridDim.x * 4) {
        int row = row0 + wave;
        __syncthreads();
        if (row < n) {
            for (int k = lane; k < K; k += 64) {
                float v = X[(size_t)row * K + k];
                if (bias != nullptr) {
                    v += bias[k];
                    if (relu) v = fmaxf(v, 0.0f);
                }
                xs[wave][k] = v;
            }
        }
        __syncthreads();
        if (row < n) {
            float acc = 0.0f;
#pragma unroll
            for (int k = 0; k < K; ++k)
                acc = fmaf(xs[wave][k], wlds[k * 64 + lane], acc);
            H[((size_t)row << 6) + lane] = __float2half(acc);
        }
    }
}

// ================= CSR gather aggregation (fp16 A, fp32 accumulate) =================
// B[d] = dinv[d]^2 * A[d] + sum_e dinv[d]*dinv[src_e] * A[src_e]
// one wave per node, lane = feature; 8 edges in flight per wave

__global__ __launch_bounds__(256) void gather_agg(
    const int* __restrict__ rowptr, const int* __restrict__ csr_src,
    const float* __restrict__ dinv, const __half* __restrict__ A,
    float* __restrict__ B, int n) {
    int gtid = blockIdx.x * blockDim.x + threadIdx.x;
    int wid = gtid >> 6, lane = gtid & 63;
    int nw = (gridDim.x * blockDim.x) >> 6;
    for (int d = wid; d < n; d += nw) {
        float dd = dinv[d];
        int e0 = rowptr[d], e1 = rowptr[d + 1];
        float acc = dd * dd * __half2float(A[((size_t)d << 6) + lane]);
        int e = e0;
        for (; e + 8 <= e1; e += 8) {
            int s[8];
            float w[8];
            float v[8];
#pragma unroll
            for (int j = 0; j < 8; ++j) s[j] = csr_src[e + j];
#pragma unroll
            for (int j = 0; j < 8; ++j) w[j] = dinv[s[j]];
#pragma unroll
            for (int j = 0; j < 8; ++j) v[j] = __half2float(A[((size_t)s[j] << 6) + lane]);
#pragma unroll
            for (int j = 0; j < 8; ++j) acc = fmaf(dd * w[j], v[j], acc);
        }
        for (; e < e1; ++e) {
            int s = csr_src[e];
            acc = fmaf(dd * dinv[s], __half2float(A[((size_t)s << 6) + lane]), acc);
        }
        B[((size_t)d << 6) + lane] = acc;
    }
}

// ================= mean pool (run-length over sorted batch) + final linear =================

__global__ __launch_bounds__(256) void pool_nodes(
    const float* __restrict__ B, const float* __restrict__ b3,
    const int* __restrict__ batch, float* __restrict__ sums,
    float* __restrict__ cnt, int n, int chunk) {
    int gtid = blockIdx.x * blockDim.x + threadIdx.x;
    int wid = gtid >> 6, lane = gtid & 63;
    int start = wid * chunk;
    if (start >= n) return;
    int end = min(n, start + chunk);
    float bl3 = b3[lane];
    int curg = batch[start];
    float acc = 0.0f;
    int cl = 0;
    for (int node = start; node < end; ++node) {
        int g = batch[node];
        if (g != curg) {
            atomicAdd(&sums[((size_t)curg << 6) + lane], acc);
            if (lane == 0) atomicAdd(&cnt[curg], (float)cl);
            acc = 0.0f; cl = 0; curg = g;
        }
        acc += B[((size_t)node << 6) + lane] + bl3;
        ++cl;
    }
    atomicAdd(&sums[((size_t)curg << 6) + lane], acc);
    if (lane == 0) atomicAdd(&cnt[curg], (float)cl);
}

__global__ void final_linear(const float* __restrict__ sums, const float* __restrict__ cnt,
                             const float* __restrict__ Wl, const float* __restrict__ bl,
                             float* __restrict__ out) {
    int idx = blockIdx.x * blockDim.x + threadIdx.x;
    if (idx >= N_GRAPHS * N_CLASSES) return;
    int g = idx / N_CLASSES, c = idx - g * N_CLASSES;
    float inv = 1.0f / fmaxf(cnt[g], 1.0f);
    float acc = bl[c];
#pragma unroll
    for (int d = 0; d < D_HID; ++d)
        acc = fmaf(sums[(g << 6) + d] * inv, Wl[d * N_CLASSES + c], acc);
    out[idx] = acc;
}

extern "C" void kernel_launch(void* const* d_in, const int* in_sizes, int n_in,
                              void* d_out, int out_size, void* d_ws, size_t ws_size,
                              hipStream_t stream) {
    const float* x     = (const float*)d_in[0];
    const int*   ei    = (const int*)d_in[1];
    const int*   batch = (const int*)d_in[2];
    const float* W1 = (const float*)d_in[3];
    const float* b1 = (const float*)d_in[4];
    const float* W2 = (const float*)d_in[5];
    const float* b2 = (const float*)d_in[6];
    const float* W3 = (const float*)d_in[7];
    const float* b3 = (const float*)d_in[8];
    const float* Wl = (const float*)d_in[9];
    const float* bl = (const float*)d_in[10];

    int n = in_sizes[0] / D_IN;
    int E = in_sizes[1] / 2;
    const int* src = ei;
    const int* dst = ei + E;

    size_t off = 0;
    auto alloc = [&](size_t bytes) {
        void* p = (char*)d_ws + off;
        off += ((bytes + 255) & ~(size_t)255);
        return p;
    };
    int*    rowptr  = (int*)alloc(((size_t)n + 1) * 4);
    int*    cursor  = (int*)alloc((size_t)n * 4);
    int*    bsum    = (int*)alloc(1024 * 4);
    int*    csr_src = (int*)alloc((size_t)E * 4);
    float*  dinv    = (float*)alloc((size_t)n * 4);
    __half* A       = (__half*)alloc((size_t)n * 64 * 2);
    float*  B       = (float*)alloc((size_t)n * 64 * 4);
    float*  sums    = (float*)alloc(N_GRAPHS * 64 * 4);
    float*  cnt     = (float*)alloc(N_GRAPHS * 4);

    int blk = 256;
    int gN  = (n + blk - 1) / blk;
    int gE  = (E + blk - 1) / blk;
    int gGemm = (n + 3) / 4;
    int nb  = (n + 1023) / 1024;

    // ---- CSR build (once, reused by all 3 layers) ----
    hipMemsetAsync(rowptr, 0, (size_t)(n + 1) * sizeof(int), stream);
    count_deg_int<<<gE, blk, 0, stream>>>(dst, rowptr + 1, E);
    compute_dinv<<<gN, blk, 0, stream>>>(rowptr + 1, dinv, n);
    scan1<<<nb, 1024, 0, stream>>>(rowptr + 1, n, bsum);
    scan2<<<1, 1024, 0, stream>>>(bsum, nb);
    if (nb > 1) scan3<<<nb - 1, 1024, 0, stream>>>(rowptr + 1, n, bsum);
    copy_cursor<<<gN, blk, 0, stream>>>(rowptr, cursor, n);
    fill_csr<<<gE, blk, 0, stream>>>(src, dst, cursor, csr_src, E);

    // ---- layer 1 ----
    gemm_nodes<D_IN><<<gGemm, blk, 0, stream>>>(x, W1, nullptr, 0, A, n);
    gather_agg<<<2048, blk, 0, stream>>>(rowptr, csr_src, dinv, A, B, n);

    // ---- layer 2 ----
    gemm_nodes<D_HID><<<gGemm, blk, 0, stream>>>(B, W2, b1, 1, A, n);
    gather_agg<<<2048, blk, 0, stream>>>(rowptr, csr_src, dinv, A, B, n);

    // ---- layer 3 ----
    gemm_nodes<D_HID><<<gGemm, blk, 0, stream>>>(B, W3, b2, 1, A, n);
    gather_agg<<<2048, blk, 0, stream>>>(rowptr, csr_src, dinv, A, B, n);

    // ---- pool + final ----
    hipMemsetAsync(sums, 0, (N_GRAPHS * 64 + N_GRAPHS) * sizeof(float), stream);
    {
        int waves = 256 * 256 / 64;  // 1024 waves
        int chunk = (n + waves - 1) / waves;
        pool_nodes<<<256, blk, 0, stream>>>(B, b3, batch, sums, cnt, n, chunk);
    }
    final_linear<<<(N_GRAPHS * N_CLASSES + blk - 1) / blk, blk, 0, stream>>>(
        sums, cnt, Wl, bl, (float*)d_out);
}

// Round 4
// 614.348 us; speedup vs baseline: 4.0800x; 1.4901x over previous
//
#include <hip/hip_runtime.h>
#include <hip/hip_fp16.h>

#define D_IN 128
#define D_HID 64
#define N_GRAPHS 1024
#define N_CLASSES 10

#define NPB 256      // nodes per bucket (power of 2)
#define MAXNB 1024   // supports n <= 262144
#define CHUNK 16384  // edges per bin_edges block

// ============ P1: bucket histogram (LDS-privatized) ============
__global__ __launch_bounds__(256) void hist_buckets(const int* __restrict__ dst, int nE, int NB,
                                                    int* __restrict__ bcnt) {
    __shared__ int h[MAXNB];
    for (int i = threadIdx.x; i < NB; i += 256) h[i] = 0;
    __syncthreads();
    int stride = gridDim.x * 256;
    for (int i = blockIdx.x * 256 + threadIdx.x; i < nE; i += stride)
        atomicAdd(&h[dst[i] >> 8], 1);
    __syncthreads();
    for (int i = threadIdx.x; i < NB; i += 256) {
        int c = h[i];
        if (c) atomicAdd(&bcnt[i], c);
    }
}

// ============ P2: exclusive scan of bucket counts ============
__global__ __launch_bounds__(1024) void scan_buckets(const int* __restrict__ bcnt, int NB, int nE,
                                                     int* __restrict__ boff, int* __restrict__ gcur) {
    __shared__ int t[1024];
    int tid = threadIdx.x;
    int v = (tid < NB) ? bcnt[tid] : 0;
    t[tid] = v;
    __syncthreads();
    for (int off = 1; off < 1024; off <<= 1) {
        int u = (tid >= off) ? t[tid - off] : 0;
        __syncthreads();
        t[tid] += u;
        __syncthreads();
    }
    int excl = t[tid] - v;
    if (tid < NB) { boff[tid] = excl; gcur[tid] = excl; }
    if (tid == 0) boff[NB] = nE;
}

// ============ P3: bin edges into bucket-contiguous packed array ============
// packed = src | (localdst << 17)   (src < 2^17, localdst < 256)
__global__ __launch_bounds__(256) void bin_edges(const int* __restrict__ src, const int* __restrict__ dst,
                                                 int nE, int NB, int* __restrict__ gcur,
                                                 int* __restrict__ binned) {
    __shared__ int h[MAXNB];
    __shared__ int base[MAXNB];
    int c0 = blockIdx.x * CHUNK;
    int c1 = min(nE, c0 + CHUNK);
    for (int i = threadIdx.x; i < NB; i += 256) h[i] = 0;
    __syncthreads();
    for (int i = c0 + threadIdx.x; i < c1; i += 256) atomicAdd(&h[dst[i] >> 8], 1);
    __syncthreads();
    for (int b = threadIdx.x; b < NB; b += 256) {
        int c = h[b];
        base[b] = c ? atomicAdd(&gcur[b], c) : 0;
        h[b] = 0;  // reuse as local cursor
    }
    __syncthreads();
    for (int i = c0 + threadIdx.x; i < c1; i += 256) {
        int d = dst[i];
        int b = d >> 8;
        int r = atomicAdd(&h[b], 1);
        binned[base[b] + r] = src[i] | ((d & 255) << 17);
    }
}

// ============ P4: per-bucket CSR finalize (rowptr, dinv, csr_src) ============
__global__ __launch_bounds__(256) void build_csr(const int* __restrict__ boff,
                                                 const int* __restrict__ binned,
                                                 int n, int nE,
                                                 int* __restrict__ rowptr, float* __restrict__ dinv,
                                                 int* __restrict__ csr_src) {
    __shared__ int cnt[NPB];
    __shared__ int soff[NPB];
    __shared__ int cur[NPB];
    int b = blockIdx.x, tid = threadIdx.x;
    int nbase = b << 8;
    int e0 = boff[b], e1 = boff[b + 1];
    cnt[tid] = 0;
    __syncthreads();
    for (int i = e0 + tid; i < e1; i += 256) atomicAdd(&cnt[binned[i] >> 17], 1);
    __syncthreads();
    // exclusive scan of cnt
    int v = cnt[tid];
    soff[tid] = v;
    __syncthreads();
    for (int off = 1; off < 256; off <<= 1) {
        int u = (tid >= off) ? soff[tid - off] : 0;
        __syncthreads();
        soff[tid] += u;
        __syncthreads();
    }
    int excl = soff[tid] - v;
    __syncthreads();
    soff[tid] = excl;
    cur[tid] = 0;
    int node = nbase + tid;
    if (node < n) {
        rowptr[node] = e0 + excl;
        dinv[node] = 1.0f / sqrtf((float)(cnt[tid] + 1));
    }
    if (b == 0 && tid == 0) rowptr[n] = nE;
    __syncthreads();
    for (int i = e0 + tid; i < e1; i += 256) {
        int e = binned[i];
        int ld = e >> 17;
        int r = atomicAdd(&cur[ld], 1);
        csr_src[e0 + soff[ld] + r] = e & 0x1FFFF;
    }
}

// ============ dense GEMM: H[n,64] = act(X + bias) @ W[K,64], fp16 output ============
template <int K>
__global__ __launch_bounds__(256) void gemm_nodes(
    const float* __restrict__ X, const float* __restrict__ W,
    const float* __restrict__ bias, int relu,
    __half* __restrict__ H, int n) {
    __shared__ float wlds[K * 64];
    __shared__ float xs[4][K];
    int tid = threadIdx.x;
    for (int i = tid; i < K * 64; i += 256) wlds[i] = W[i];
    int wave = tid >> 6, lane = tid & 63;
    for (int row0 = blockIdx.x * 4; row0 < n; row0 += gridDim.x * 4) {
        int row = row0 + wave;
        __syncthreads();
        if (row < n) {
            for (int k = lane; k < K; k += 64) {
                float v = X[(size_t)row * K + k];
                if (bias != nullptr) {
                    v += bias[k];
                    if (relu) v = fmaxf(v, 0.0f);
                }
                xs[wave][k] = v;
            }
        }
        __syncthreads();
        if (row < n) {
            float acc = 0.0f;
#pragma unroll
            for (int k = 0; k < K; ++k)
                acc = fmaf(xs[wave][k], wlds[k * 64 + lane], acc);
            H[((size_t)row << 6) + lane] = __float2half(acc);
        }
    }
}

// ============ CSR gather aggregation (fp16 A, fp32 accumulate) ============
__global__ __launch_bounds__(256) void gather_agg(
    const int* __restrict__ rowptr, const int* __restrict__ csr_src,
    const float* __restrict__ dinv, const __half* __restrict__ A,
    float* __restrict__ B, int n) {
    int gtid = blockIdx.x * blockDim.x + threadIdx.x;
    int wid = gtid >> 6, lane = gtid & 63;
    int nw = (gridDim.x * blockDim.x) >> 6;
    for (int d = wid; d < n; d += nw) {
        float dd = dinv[d];
        int e0 = rowptr[d], e1 = rowptr[d + 1];
        float acc = dd * dd * __half2float(A[((size_t)d << 6) + lane]);
        int e = e0;
        for (; e + 8 <= e1; e += 8) {
            int s[8];
            float w[8], v[8];
#pragma unroll
            for (int j = 0; j < 8; ++j) s[j] = csr_src[e + j];
#pragma unroll
            for (int j = 0; j < 8; ++j) w[j] = dinv[s[j]];
#pragma unroll
            for (int j = 0; j < 8; ++j) v[j] = __half2float(A[((size_t)s[j] << 6) + lane]);
#pragma unroll
            for (int j = 0; j < 8; ++j) acc = fmaf(dd * w[j], v[j], acc);
        }
        for (; e < e1; ++e) {
            int s = csr_src[e];
            acc = fmaf(dd * dinv[s], __half2float(A[((size_t)s << 6) + lane]), acc);
        }
        B[((size_t)d << 6) + lane] = acc;
    }
}

// ============ mean pool (run-length over sorted batch) + final linear ============
__global__ __launch_bounds__(256) void pool_nodes(
    const float* __restrict__ B, const float* __restrict__ b3,
    const int* __restrict__ batch, float* __restrict__ sums,
    float* __restrict__ gcnt, int n, int chunk) {
    int gtid = blockIdx.x * blockDim.x + threadIdx.x;
    int wid = gtid >> 6, lane = gtid & 63;
    int start = wid * chunk;
    if (start >= n) return;
    int end = min(n, start + chunk);
    float bl3 = b3[lane];
    int curg = batch[start];
    float acc = 0.0f;
    int cl = 0;
    for (int node = start; node < end; ++node) {
        int g = batch[node];
        if (g != curg) {
            atomicAdd(&sums[((size_t)curg << 6) + lane], acc);
            if (lane == 0) atomicAdd(&gcnt[curg], (float)cl);
            acc = 0.0f; cl = 0; curg = g;
        }
        acc += B[((size_t)node << 6) + lane] + bl3;
        ++cl;
    }
    atomicAdd(&sums[((size_t)curg << 6) + lane], acc);
    if (lane == 0) atomicAdd(&gcnt[curg], (float)cl);
}

__global__ void final_linear(const float* __restrict__ sums, const float* __restrict__ gcnt,
                             const float* __restrict__ Wl, const float* __restrict__ bl,
                             float* __restrict__ out) {
    int idx = blockIdx.x * blockDim.x + threadIdx.x;
    if (idx >= N_GRAPHS * N_CLASSES) return;
    int g = idx / N_CLASSES, c = idx - g * N_CLASSES;
    float inv = 1.0f / fmaxf(gcnt[g], 1.0f);
    float acc = bl[c];
#pragma unroll
    for (int d = 0; d < D_HID; ++d)
        acc = fmaf(sums[(g << 6) + d] * inv, Wl[d * N_CLASSES + c], acc);
    out[idx] = acc;
}

extern "C" void kernel_launch(void* const* d_in, const int* in_sizes, int n_in,
                              void* d_out, int out_size, void* d_ws, size_t ws_size,
                              hipStream_t stream) {
    const float* x     = (const float*)d_in[0];
    const int*   ei    = (const int*)d_in[1];
    const int*   batch = (const int*)d_in[2];
    const float* W1 = (const float*)d_in[3];
    const float* b1 = (const float*)d_in[4];
    const float* W2 = (const float*)d_in[5];
    const float* b2 = (const float*)d_in[6];
    const float* W3 = (const float*)d_in[7];
    const float* b3 = (const float*)d_in[8];
    const float* Wl = (const float*)d_in[9];
    const float* bl = (const float*)d_in[10];

    int n = in_sizes[0] / D_IN;
    int E = in_sizes[1] / 2;
    const int* src = ei;
    const int* dst = ei + E;
    int NB = (n + NPB - 1) / NPB;  // 391 for n=100000

    size_t off = 0;
    auto alloc = [&](size_t bytes) {
        void* p = (char*)d_ws + off;
        off += ((bytes + 255) & ~(size_t)255);
        return p;
    };
    int*    rowptr  = (int*)alloc(((size_t)n + 1) * 4);
    int*    bcnt    = (int*)alloc(MAXNB * 4);
    int*    boff    = (int*)alloc((MAXNB + 1) * 4);
    int*    gcur    = (int*)alloc(MAXNB * 4);
    int*    binned  = (int*)alloc((size_t)E * 4);      // aliased below as A (fp16 n*64)
    int*    csr_src = (int*)alloc((size_t)E * 4);
    float*  dinv    = (float*)alloc((size_t)n * 4);
    float*  B       = (float*)alloc((size_t)n * 64 * 4);
    float*  sums    = (float*)alloc(N_GRAPHS * 64 * 4);
    float*  gcnt    = (float*)alloc(N_GRAPHS * 4);
    __half* A       = (__half*)binned;  // binned (E*4 B) dead before A (n*128 B) is written

    int blk = 256;
    int gGemm = (n + 3) / 4;
    int gBin  = (E + CHUNK - 1) / CHUNK;

    // ---- CSR build (bucketed; once, reused by all 3 layers) ----
    hipMemsetAsync(bcnt, 0, MAXNB * sizeof(int), stream);
    hist_buckets<<<256, blk, 0, stream>>>(dst, E, NB, bcnt);
    scan_buckets<<<1, 1024, 0, stream>>>(bcnt, NB, E, boff, gcur);
    bin_edges<<<gBin, blk, 0, stream>>>(src, dst, E, NB, gcur, binned);
    build_csr<<<NB, blk, 0, stream>>>(boff, binned, n, E, rowptr, dinv, csr_src);

    // ---- layer 1 ----
    gemm_nodes<D_IN><<<gGemm, blk, 0, stream>>>(x, W1, nullptr, 0, A, n);
    gather_agg<<<2048, blk, 0, stream>>>(rowptr, csr_src, dinv, A, B, n);

    // ---- layer 2 ----
    gemm_nodes<D_HID><<<gGemm, blk, 0, stream>>>(B, W2, b1, 1, A, n);
    gather_agg<<<2048, blk, 0, stream>>>(rowptr, csr_src, dinv, A, B, n);

    // ---- layer 3 ----
    gemm_nodes<D_HID><<<gGemm, blk, 0, stream>>>(B, W3, b2, 1, A, n);
    gather_agg<<<2048, blk, 0, stream>>>(rowptr, csr_src, dinv, A, B, n);

    // ---- pool + final ----
    hipMemsetAsync(sums, 0, (N_GRAPHS * 64 + N_GRAPHS) * sizeof(float), stream);
    {
        int waves = 256 * 256 / 64;  // 1024 waves
        int chunk = (n + waves - 1) / waves;
        pool_nodes<<<256, blk, 0, stream>>>(B, b3, batch, sums, gcnt, n, chunk);
    }
    final_linear<<<(N_GRAPHS * N_CLASSES + blk - 1) / blk, blk, 0, stream>>>(
        sums, gcnt, Wl, bl, (float*)d_out);
}

// Round 5
// 399.397 us; speedup vs baseline: 6.2757x; 1.5382x over previous
//
#include <hip/hip_runtime.h>
#include <hip/hip_fp16.h>

#define D_IN 128
#define D_HID 64
#define N_GRAPHS 1024
#define N_CLASSES 10

#define NPB 256      // nodes per bucket (power of 2)
#define MAXNB 1024   // supports n <= 262144
#define CHUNK 16384  // edges per bin_edges block

typedef __attribute__((ext_vector_type(8))) short bf16x8;
typedef __attribute__((ext_vector_type(4))) float f32x4;

__device__ __forceinline__ unsigned bf16_rne(float f) {
    unsigned u = __float_as_uint(f);
    return (u + 0x7FFF + ((u >> 16) & 1)) >> 16;
}

// ============ P1: bucket histogram (LDS-privatized) ============
__global__ __launch_bounds__(256) void hist_buckets(const int* __restrict__ dst, int nE, int NB,
                                                    int* __restrict__ bcnt) {
    __shared__ int h[MAXNB];
    for (int i = threadIdx.x; i < NB; i += 256) h[i] = 0;
    __syncthreads();
    int stride = gridDim.x * 256;
    for (int i = blockIdx.x * 256 + threadIdx.x; i < nE; i += stride)
        atomicAdd(&h[dst[i] >> 8], 1);
    __syncthreads();
    for (int i = threadIdx.x; i < NB; i += 256) {
        int c = h[i];
        if (c) atomicAdd(&bcnt[i], c);
    }
}

// ============ P2: exclusive scan of bucket counts ============
__global__ __launch_bounds__(1024) void scan_buckets(const int* __restrict__ bcnt, int NB, int nE,
                                                     int* __restrict__ boff, int* __restrict__ gcur) {
    __shared__ int t[1024];
    int tid = threadIdx.x;
    int v = (tid < NB) ? bcnt[tid] : 0;
    t[tid] = v;
    __syncthreads();
    for (int off = 1; off < 1024; off <<= 1) {
        int u = (tid >= off) ? t[tid - off] : 0;
        __syncthreads();
        t[tid] += u;
        __syncthreads();
    }
    int excl = t[tid] - v;
    if (tid < NB) { boff[tid] = excl; gcur[tid] = excl; }
    if (tid == 0) boff[NB] = nE;
}

// ============ P3: bin edges into bucket-contiguous packed array ============
__global__ __launch_bounds__(256) void bin_edges(const int* __restrict__ src, const int* __restrict__ dst,
                                                 int nE, int NB, int* __restrict__ gcur,
                                                 int* __restrict__ binned) {
    __shared__ int h[MAXNB];
    __shared__ int base[MAXNB];
    int c0 = blockIdx.x * CHUNK;
    int c1 = min(nE, c0 + CHUNK);
    for (int i = threadIdx.x; i < NB; i += 256) h[i] = 0;
    __syncthreads();
    for (int i = c0 + threadIdx.x; i < c1; i += 256) atomicAdd(&h[dst[i] >> 8], 1);
    __syncthreads();
    for (int b = threadIdx.x; b < NB; b += 256) {
        int c = h[b];
        base[b] = c ? atomicAdd(&gcur[b], c) : 0;
        h[b] = 0;
    }
    __syncthreads();
    for (int i = c0 + threadIdx.x; i < c1; i += 256) {
        int d = dst[i];
        int b = d >> 8;
        int r = atomicAdd(&h[b], 1);
        binned[base[b] + r] = src[i] | ((d & 255) << 17);
    }
}

// ============ P4: per-bucket CSR finalize (rowptr, dinv, csr_src) ============
__global__ __launch_bounds__(256) void build_csr(const int* __restrict__ boff,
                                                 const int* __restrict__ binned,
                                                 int n, int nE,
                                                 int* __restrict__ rowptr, float* __restrict__ dinv,
                                                 int* __restrict__ csr_src) {
    __shared__ int cnt[NPB];
    __shared__ int soff[NPB];
    __shared__ int cur[NPB];
    int b = blockIdx.x, tid = threadIdx.x;
    int nbase = b << 8;
    int e0 = boff[b], e1 = boff[b + 1];
    cnt[tid] = 0;
    __syncthreads();
    for (int i = e0 + tid; i < e1; i += 256) atomicAdd(&cnt[binned[i] >> 17], 1);
    __syncthreads();
    int v = cnt[tid];
    soff[tid] = v;
    __syncthreads();
    for (int off = 1; off < 256; off <<= 1) {
        int u = (tid >= off) ? soff[tid - off] : 0;
        __syncthreads();
        soff[tid] += u;
        __syncthreads();
    }
    int excl = soff[tid] - v;
    __syncthreads();
    soff[tid] = excl;
    cur[tid] = 0;
    int node = nbase + tid;
    if (node < n) {
        rowptr[node] = e0 + excl;
        dinv[node] = 1.0f / sqrtf((float)(cnt[tid] + 1));
    }
    if (b == 0 && tid == 0) rowptr[n] = nE;
    __syncthreads();
    for (int i = e0 + tid; i < e1; i += 256) {
        int e = binned[i];
        int ld = e >> 17;
        int r = atomicAdd(&cur[ld], 1);
        csr_src[e0 + soff[ld] + r] = e & 0x1FFFF;
    }
}

// ============ pack W into MFMA B-fragment order, split bf16 hi/lo ============
// slot s = (kstep, nf, lane): element j -> W[kstep*32 + (lane>>4)*8 + j][nf*16 + (lane&15)]
template <int K>
__global__ void pack_w(const float* __restrict__ W, short* __restrict__ hi, short* __restrict__ lo) {
    constexpr int SLOTS = (K / 32) * 4 * 64;
    for (int s = threadIdx.x; s < SLOTS; s += 256) {
        int lane = s & 63, nf = (s >> 6) & 3, ks = s >> 8;
        int fq = lane >> 4, fr = lane & 15;
#pragma unroll
        for (int j = 0; j < 8; ++j) {
            int k = ks * 32 + fq * 8 + j;
            int c = nf * 16 + fr;
            float v = W[k * 64 + c];
            unsigned hb = bf16_rne(v);
            float hf = __uint_as_float(hb << 16);
            float l = v - hf;
            hi[s * 8 + j] = (short)hb;
            lo[s * 8 + j] = (short)bf16_rne(l);
        }
    }
}

// ============ MFMA GEMM: H[n,64] = act(X + bias) @ W[K,64], fp16 out ============
// split-bf16 3-term: Xhi@Whi + Xlo@Whi + Xhi@Wlo (rel err ~2^-17)
template <int K>
__global__ __launch_bounds__(256) void gemm_mfma(
    const float* __restrict__ X, const short* __restrict__ whi, const short* __restrict__ wlo,
    const float* __restrict__ bias, int relu, __half* __restrict__ H, int n) {
    constexpr int KS = K / 32;
    int wave = threadIdx.x >> 6, lane = threadIdx.x & 63;
    int fr = lane & 15, fq = lane >> 4;
    int rowbase = blockIdx.x * 64 + wave * 16;
    int rclamp = min(rowbase + fr, n - 1);
    f32x4 acc[4] = {{0,0,0,0},{0,0,0,0},{0,0,0,0},{0,0,0,0}};
#pragma unroll
    for (int ks = 0; ks < KS; ++ks) {
        const float* xp = X + (size_t)rclamp * K + ks * 32 + fq * 8;
        float xv[8];
        *(f32x4*)&xv[0] = *(const f32x4*)xp;
        *(f32x4*)&xv[4] = *(const f32x4*)(xp + 4);
        if (bias != nullptr) {
            const float* bp = bias + ks * 32 + fq * 8;
#pragma unroll
            for (int j = 0; j < 8; ++j) {
                float v = xv[j] + bp[j];
                if (relu) v = fmaxf(v, 0.0f);
                xv[j] = v;
            }
        }
        bf16x8 ahi, alo;
#pragma unroll
        for (int j = 0; j < 8; ++j) {
            unsigned hb = bf16_rne(xv[j]);
            float hf = __uint_as_float(hb << 16);
            ahi[j] = (short)hb;
            alo[j] = (short)bf16_rne(xv[j] - hf);
        }
        const short* whp = whi + (size_t)(ks * 4) * 64 * 8 + lane * 8;
        const short* wlp = wlo + (size_t)(ks * 4) * 64 * 8 + lane * 8;
#pragma unroll
        for (int nf = 0; nf < 4; ++nf) {
            bf16x8 bhi = *(const bf16x8*)(whp + nf * 512);
            bf16x8 blo = *(const bf16x8*)(wlp + nf * 512);
            acc[nf] = __builtin_amdgcn_mfma_f32_16x16x32_bf16(ahi, bhi, acc[nf], 0, 0, 0);
            acc[nf] = __builtin_amdgcn_mfma_f32_16x16x32_bf16(alo, bhi, acc[nf], 0, 0, 0);
            acc[nf] = __builtin_amdgcn_mfma_f32_16x16x32_bf16(ahi, blo, acc[nf], 0, 0, 0);
        }
    }
    // C/D: col = nf*16 + (lane&15), row = rowbase + (lane>>4)*4 + reg
#pragma unroll
    for (int nf = 0; nf < 4; ++nf) {
#pragma unroll
        for (int reg = 0; reg < 4; ++reg) {
            int r = rowbase + fq * 4 + reg;
            if (r < n) H[((size_t)r << 6) + nf * 16 + fr] = __float2half(acc[nf][reg]);
        }
    }
}

// ============ CSR gather aggregation (fp16 A, fp32 accumulate) ============
// 16 lanes per edge (8 B/lane), 4 edge-slots per wave, unroll 2
__global__ __launch_bounds__(256) void gather_agg(
    const int* __restrict__ rowptr, const int* __restrict__ csr_src,
    const float* __restrict__ dinv, const __half* __restrict__ A,
    float* __restrict__ B, int n) {
    int gtid = blockIdx.x * 256 + threadIdx.x;
    int wid = gtid >> 6, lane = gtid & 63;
    int nw = (gridDim.x * 256) >> 6;
    int slot = lane >> 4, fl = lane & 15;
    for (int d = wid; d < n; d += nw) {
        float dd = dinv[d];
        int e0 = rowptr[d], e1 = rowptr[d + 1];
        float4 acc = make_float4(0.f, 0.f, 0.f, 0.f);
        if (slot == 0) {
            uint2 q = *(const uint2*)(A + ((size_t)d << 6) + (fl << 2));
            float2 f0 = __half22float2(*(__half2*)&q.x);
            float2 f1 = __half22float2(*(__half2*)&q.y);
            float w = dd * dd;
            acc = make_float4(w * f0.x, w * f0.y, w * f1.x, w * f1.y);
        }
        int e = e0 + slot;
        for (; e + 4 < e1; e += 8) {
            int s0 = csr_src[e], s1 = csr_src[e + 4];
            float w0 = dd * dinv[s0], w1 = dd * dinv[s1];
            uint2 q0 = *(const uint2*)(A + ((size_t)s0 << 6) + (fl << 2));
            uint2 q1 = *(const uint2*)(A + ((size_t)s1 << 6) + (fl << 2));
            float2 a0 = __half22float2(*(__half2*)&q0.x);
            float2 a1 = __half22float2(*(__half2*)&q0.y);
            float2 b0 = __half22float2(*(__half2*)&q1.x);
            float2 b1 = __half22float2(*(__half2*)&q1.y);
            acc.x = fmaf(w0, a0.x, acc.x); acc.y = fmaf(w0, a0.y, acc.y);
            acc.z = fmaf(w0, a1.x, acc.z); acc.w = fmaf(w0, a1.y, acc.w);
            acc.x = fmaf(w1, b0.x, acc.x); acc.y = fmaf(w1, b0.y, acc.y);
            acc.z = fmaf(w1, b1.x, acc.z); acc.w = fmaf(w1, b1.y, acc.w);
        }
        if (e < e1) {
            int s = csr_src[e];
            float w = dd * dinv[s];
            uint2 q = *(const uint2*)(A + ((size_t)s << 6) + (fl << 2));
            float2 a0 = __half22float2(*(__half2*)&q.x);
            float2 a1 = __half22float2(*(__half2*)&q.y);
            acc.x = fmaf(w, a0.x, acc.x); acc.y = fmaf(w, a0.y, acc.y);
            acc.z = fmaf(w, a1.x, acc.z); acc.w = fmaf(w, a1.y, acc.w);
        }
        // reduce 4 slots -> slot 0
        acc.x += __shfl_xor(acc.x, 16); acc.y += __shfl_xor(acc.y, 16);
        acc.z += __shfl_xor(acc.z, 16); acc.w += __shfl_xor(acc.w, 16);
        acc.x += __shfl_xor(acc.x, 32); acc.y += __shfl_xor(acc.y, 32);
        acc.z += __shfl_xor(acc.z, 32); acc.w += __shfl_xor(acc.w, 32);
        if (slot == 0) *(float4*)(B + ((size_t)d << 6) + (fl << 2)) = acc;
    }
}

// ============ mean pool (run-length over sorted batch) + final linear ============
__global__ __launch_bounds__(256) void pool_nodes(
    const float* __restrict__ B, const float* __restrict__ b3,
    const int* __restrict__ batch, float* __restrict__ sums,
    float* __restrict__ gcnt, int n, int chunk) {
    int gtid = blockIdx.x * blockDim.x + threadIdx.x;
    int wid = gtid >> 6, lane = gtid & 63;
    int start = wid * chunk;
    if (start >= n) return;
    int end = min(n, start + chunk);
    float bl3 = b3[lane];
    int curg = batch[start];
    float acc = 0.0f;
    int cl = 0;
    for (int node = start; node < end; ++node) {
        int g = batch[node];
        if (g != curg) {
            atomicAdd(&sums[((size_t)curg << 6) + lane], acc);
            if (lane == 0) atomicAdd(&gcnt[curg], (float)cl);
            acc = 0.0f; cl = 0; curg = g;
        }
        acc += B[((size_t)node << 6) + lane] + bl3;
        ++cl;
    }
    atomicAdd(&sums[((size_t)curg << 6) + lane], acc);
    if (lane == 0) atomicAdd(&gcnt[curg], (float)cl);
}

__global__ void final_linear(const float* __restrict__ sums, const float* __restrict__ gcnt,
                             const float* __restrict__ Wl, const float* __restrict__ bl,
                             float* __restrict__ out) {
    int idx = blockIdx.x * blockDim.x + threadIdx.x;
    if (idx >= N_GRAPHS * N_CLASSES) return;
    int g = idx / N_CLASSES, c = idx - g * N_CLASSES;
    float inv = 1.0f / fmaxf(gcnt[g], 1.0f);
    float acc = bl[c];
#pragma unroll
    for (int d = 0; d < D_HID; ++d)
        acc = fmaf(sums[(g << 6) + d] * inv, Wl[d * N_CLASSES + c], acc);
    out[idx] = acc;
}

extern "C" void kernel_launch(void* const* d_in, const int* in_sizes, int n_in,
                              void* d_out, int out_size, void* d_ws, size_t ws_size,
                              hipStream_t stream) {
    const float* x     = (const float*)d_in[0];
    const int*   ei    = (const int*)d_in[1];
    const int*   batch = (const int*)d_in[2];
    const float* W1 = (const float*)d_in[3];
    const float* b1 = (const float*)d_in[4];
    const float* W2 = (const float*)d_in[5];
    const float* b2 = (const float*)d_in[6];
    const float* W3 = (const float*)d_in[7];
    const float* b3 = (const float*)d_in[8];
    const float* Wl = (const float*)d_in[9];
    const float* bl = (const float*)d_in[10];

    int n = in_sizes[0] / D_IN;
    int E = in_sizes[1] / 2;
    const int* src = ei;
    const int* dst = ei + E;
    int NB = (n + NPB - 1) / NPB;

    size_t off = 0;
    auto alloc = [&](size_t bytes) {
        void* p = (char*)d_ws + off;
        off += ((bytes + 255) & ~(size_t)255);
        return p;
    };
    int*    rowptr  = (int*)alloc(((size_t)n + 1) * 4);
    int*    bcnt    = (int*)alloc(MAXNB * 4);
    int*    boff    = (int*)alloc((MAXNB + 1) * 4);
    int*    gcur    = (int*)alloc(MAXNB * 4);
    int*    binned  = (int*)alloc((size_t)E * 4);      // aliased below as A (fp16 n*64)
    int*    csr_src = (int*)alloc((size_t)E * 4);
    float*  dinv    = (float*)alloc((size_t)n * 4);
    float*  B       = (float*)alloc((size_t)n * 64 * 4);
    float*  sums    = (float*)alloc(N_GRAPHS * 64 * 4);
    float*  gcnt    = (float*)alloc(N_GRAPHS * 4);
    short*  w1hi    = (short*)alloc(4 * 4 * 64 * 8 * 2);
    short*  w1lo    = (short*)alloc(4 * 4 * 64 * 8 * 2);
    short*  w2hi    = (short*)alloc(2 * 4 * 64 * 8 * 2);
    short*  w2lo    = (short*)alloc(2 * 4 * 64 * 8 * 2);
    short*  w3hi    = (short*)alloc(2 * 4 * 64 * 8 * 2);
    short*  w3lo    = (short*)alloc(2 * 4 * 64 * 8 * 2);
    __half* A       = (__half*)binned;  // binned dead before A is written

    int blk = 256;
    int gBin  = (E + CHUNK - 1) / CHUNK;
    int gGemm = (n + 63) / 64;

    // ---- CSR build (bucketed; once, reused by all 3 layers) ----
    hipMemsetAsync(bcnt, 0, MAXNB * sizeof(int), stream);
    hist_buckets<<<256, blk, 0, stream>>>(dst, E, NB, bcnt);
    scan_buckets<<<1, 1024, 0, stream>>>(bcnt, NB, E, boff, gcur);
    bin_edges<<<gBin, blk, 0, stream>>>(src, dst, E, NB, gcur, binned);
    build_csr<<<NB, blk, 0, stream>>>(boff, binned, n, E, rowptr, dinv, csr_src);

    // ---- pack weights (once) ----
    pack_w<D_IN><<<1, blk, 0, stream>>>(W1, w1hi, w1lo);
    pack_w<D_HID><<<1, blk, 0, stream>>>(W2, w2hi, w2lo);
    pack_w<D_HID><<<1, blk, 0, stream>>>(W3, w3hi, w3lo);

    // ---- layer 1 ----
    gemm_mfma<D_IN><<<gGemm, blk, 0, stream>>>(x, w1hi, w1lo, nullptr, 0, A, n);
    gather_agg<<<2048, blk, 0, stream>>>(rowptr, csr_src, dinv, A, B, n);

    // ---- layer 2 ----
    gemm_mfma<D_HID><<<gGemm, blk, 0, stream>>>(B, w2hi, w2lo, b1, 1, A, n);
    gather_agg<<<2048, blk, 0, stream>>>(rowptr, csr_src, dinv, A, B, n);

    // ---- layer 3 ----
    gemm_mfma<D_HID><<<gGemm, blk, 0, stream>>>(B, w3hi, w3lo, b2, 1, A, n);
    gather_agg<<<2048, blk, 0, stream>>>(rowptr, csr_src, dinv, A, B, n);

    // ---- pool + final ----
    hipMemsetAsync(sums, 0, (N_GRAPHS * 64 + N_GRAPHS) * sizeof(float), stream);
    {
        int waves = 256 * 256 / 64;
        int chunk = (n + waves - 1) / waves;
        pool_nodes<<<256, blk, 0, stream>>>(B, b3, batch, sums, gcnt, n, chunk);
    }
    final_linear<<<(N_GRAPHS * N_CLASSES + blk - 1) / blk, blk, 0, stream>>>(
        sums, gcnt, Wl, bl, (float*)d_out);
}